// Round 3
// baseline (276.450 us; speedup 1.0000x reference)
//
#include <hip/hip_runtime.h>
#include <cmath>

// HungarianMatcher cost matrix C[16,1500,2400] = 5*L1 + focal_class + 2*(-GIoU)
// R3: loop-interchanged so target data lives in REGISTERS across all 16 queries.
//  - block = 256 thr: 16 queries x 1024-target tile (grid 1500 x 3)
//  - per thread: 4 targets staged in regs (box, corners, area, class-row offset)
//  - focal class table fp32 [256][20-padded]: ONE ds_read_b128 per (t, 4-query
//    tile) -> per-element LDS ~3 cyc (was ~44 with per-element gathers in R2)
//  - queries tiled 4x4; per-element ~30 VALU + 1 coalesced dword store
// Floors: stores 230MB -> 37us, VALU ~26us. Harness re-poison fill (~140us)
// is additive in dur_us and outside our control.

namespace {
constexpr int kBS = 16, kQ = 1500, kK = 256, kNT = 150;
constexpr int kT  = kBS * kNT;   // 2400 targets
constexpr int kN  = kBS * kQ;    // 24000 queries
constexpr int kQB = 16;          // queries per block
constexpr int kTT = 1024;        // target tile (tiles: 1024,1024,352)
constexpr int kTiles = 3;
constexpr int kFS = 20;          // focal row stride in floats (80B: bank-spread)
constexpr float kAlpha = 0.25f;
constexpr float kEps   = 1e-8f;
}

__global__ __launch_bounds__(256, 4)
void matcher_cost_kernel(const float* __restrict__ logits,   // [N,256]
                         const float* __restrict__ pboxes,   // [N,4] cxcywh
                         const float* __restrict__ tboxes,   // [T,4] cxcywh
                         const int*   __restrict__ tids,     // [T]
                         float* __restrict__ out)            // [N,T]
{
    __shared__ float4 s_box[kTT];           // 16 KB
    __shared__ unsigned char s_cid[kTT];    // 1 KB
    __shared__ float s_fcl[kK * kFS];       // 20 KB: [class][q0..15, pad to 20]

    const int tid = threadIdx.x;
    const int n0  = blockIdx.x * kQB;
    const int t0  = blockIdx.y * kTT;
    const int tsz = min(kTT, kT - t0);

    // ---- stage target tile into LDS ----
    const float4* tb4 = reinterpret_cast<const float4*>(tboxes);
    for (int j = tid; j < tsz; j += 256) {
        s_box[j] = tb4[t0 + j];
        s_cid[j] = (unsigned char)tids[t0 + j];
    }

    // ---- focal class-cost table, fp32, row = class (thread), col = query ----
#pragma unroll
    for (int q = 0; q < kQB; ++q) {
        const float x   = logits[(size_t)(n0 + q) * kK + tid];
        const float p   = __builtin_amdgcn_rcpf(1.0f + __expf(-x));
        const float omp = 1.0f - p;
        const float cc  = -kAlpha * omp * omp * __logf(p + kEps)
                        + (1.0f - kAlpha) * p * p * __logf(omp + kEps);
        s_fcl[tid * kFS + q] = cc;
    }
    __syncthreads();   // only barrier; LDS read-only below

    // ---- stage this thread's 4 targets into registers ----
    float bcx[4], bcy[4], bwv[4], bhv[4];
    float tx1[4], tx2[4], ty1[4], ty2[4], barea[4];
    int   cofs[4];
    bool  act[4];
#pragma unroll
    for (int g = 0; g < 4; ++g) {
        const int t = tid + 256 * g;
        act[g] = (t < tsz);
        if (256 * g < tsz) {            // wave-uniform group guard
            const float4 b = s_box[t];
            bcx[g] = b.x; bcy[g] = b.y; bwv[g] = b.z; bhv[g] = b.w;
            tx1[g] = b.x - 0.5f * b.z;  tx2[g] = b.x + 0.5f * b.z;
            ty1[g] = b.y - 0.5f * b.w;  ty2[g] = b.y + 0.5f * b.w;
            barea[g] = b.z * b.w;
            cofs[g] = (int)s_cid[t] * kFS;
        }
    }

    // ---- main: 4 query-tiles x 4 target-groups x 4 queries ----
    for (int qt = 0; qt < 4; ++qt) {
        float pcx[4], pcy[4], pw[4], ph[4];
        float px1[4], px2[4], py1[4], py2[4], parea[4];
#pragma unroll
        for (int qq = 0; qq < 4; ++qq) {
            const int n = n0 + qt * 4 + qq;
            pcx[qq] = pboxes[n * 4 + 0];
            pcy[qq] = pboxes[n * 4 + 1];
            pw[qq]  = pboxes[n * 4 + 2];
            ph[qq]  = pboxes[n * 4 + 3];
            px1[qq] = pcx[qq] - 0.5f * pw[qq];  px2[qq] = pcx[qq] + 0.5f * pw[qq];
            py1[qq] = pcy[qq] - 0.5f * ph[qq];  py2[qq] = pcy[qq] + 0.5f * ph[qq];
            parea[qq] = pw[qq] * ph[qq];
        }
        float* __restrict__ base = out + (size_t)(n0 + qt * 4) * kT + t0;

#pragma unroll
        for (int g = 0; g < 4; ++g) {
            if (256 * g >= tsz) continue;      // wave-uniform
            // one gather serves 4 queries (16B aligned: cofs*4=80c, +16*qt)
            const float4 f4 =
                *reinterpret_cast<const float4*>(&s_fcl[cofs[g] + qt * 4]);
            const float fc[4] = {f4.x, f4.y, f4.z, f4.w};
#pragma unroll
            for (int qq = 0; qq < 4; ++qq) {
                const float cb = fabsf(pcx[qq] - bcx[g]) + fabsf(pcy[qq] - bcy[g])
                               + fabsf(pw[qq] - bwv[g]) + fabsf(ph[qq] - bhv[g]);
                const float ow = fminf(px2[qq], tx2[g]) - fmaxf(px1[qq], tx1[g]);
                const float oh = fminf(py2[qq], ty2[g]) - fmaxf(py1[qq], ty1[g]);
                const float iw = fmaxf(ow, 0.0f), ih = fmaxf(oh, 0.0f);
                const float ew = pw[qq] + bwv[g] - ow;
                const float eh = ph[qq] + bhv[g] - oh;
                const float inter = iw * ih;
                const float uni   = parea[qq] + barea[g] - inter;
                const float earea = ew * eh;
                // giou = inter/uni - 1 + uni/earea; out = 5cb+cc+2 - 2*frac
                const float r    = __builtin_amdgcn_rcpf(uni * earea);
                const float frac = fmaf(uni, uni, inter * earea) * r;
                const float v    = fmaf(5.0f, cb, fc[qq] + 2.0f) - 2.0f * frac;
                if (act[g]) base[(size_t)qq * kT + 256 * g + tid] = v;
            }
        }
    }
}

extern "C" void kernel_launch(void* const* d_in, const int* in_sizes, int n_in,
                              void* d_out, int out_size, void* d_ws, size_t ws_size,
                              hipStream_t stream) {
    const float* logits = (const float*)d_in[0];   // [16,1500,256]
    const float* pboxes = (const float*)d_in[1];   // [16,1500,4]
    const float* tboxes = (const float*)d_in[2];   // [2400,4]
    const int*   tids   = (const int*)d_in[3];     // [2400]
    float* out = (float*)d_out;                    // [16,1500,2400] fp32

    dim3 grid(kN / kQB, kTiles);   // 1500 x 3
    dim3 block(256);
    hipLaunchKernelGGL(matcher_cost_kernel, grid, block, 0, stream,
                       logits, pboxes, tboxes, tids, out);
}